// Round 9
// baseline (137.555 us; speedup 1.0000x reference)
//
#include <hip/hip_runtime.h>
#include <hip/hip_bf16.h>
#include <math.h>

#define TT 577          // real tokens per n
#define TP 640          // padded tokens per n
#define TBL 37          // t-blocks of 16 tokens per n (37*16 = 592 >= 577)
#define CCH 768         // channels
#define KR 64           // regions
#define NB 64           // batch

typedef __attribute__((ext_vector_type(8))) short bf16x8;
typedef __attribute__((ext_vector_type(8))) unsigned short ushort8;
typedef __attribute__((ext_vector_type(4))) float f32x4;

static constexpr float EPSF = 1e-12f;

// float -> bf16 bits via HW conversion (RNE)
static __device__ inline unsigned short f2bf(float f) {
    return __bfloat16_as_ushort(__float2bfloat16(f));
}

// ---------------------------------------------------------------------------
// Kernel 0: one-time prep. (a) conv_w fp32 -> bf16 ws_w[64][768];
// (b) zero ws_a row tails t in [592,640) (read by k_vlad, never written by
// k_logits). Grid 64 x 256.
// ---------------------------------------------------------------------------
__global__ __launch_bounds__(256) void k_prep(
    const float* __restrict__ conv_w,
    unsigned short* __restrict__ ws_w,
    unsigned short* __restrict__ ws_a)
{
    const int g = blockIdx.x * 256 + threadIdx.x;   // [0, 16384)
    if (g < 6144) {                                 // 6144 * 8 = 49152 = 64*768
        const float* s = conv_w + (size_t)g * 8;
        float4 v0 = *reinterpret_cast<const float4*>(s);
        float4 v1 = *reinterpret_cast<const float4*>(s + 4);
        ushort8 o;
        o[0]=f2bf(v0.x); o[1]=f2bf(v0.y); o[2]=f2bf(v0.z); o[3]=f2bf(v0.w);
        o[4]=f2bf(v1.x); o[5]=f2bf(v1.y); o[6]=f2bf(v1.z); o[7]=f2bf(v1.w);
        *reinterpret_cast<ushort8*>(ws_w + (size_t)g * 8) = o;
    }
    if (g < 4096) {                                 // 4096 rows = 64 n * 64 kr
        unsigned short* d = ws_a + (size_t)g * TP + 592;
        ushort8 z = {0,0,0,0,0,0,0,0};
        #pragma unroll
        for (int i = 0; i < 6; ++i)
            *reinterpret_cast<ushort8*>(d + i * 8) = z;
    }
}

// ---------------------------------------------------------------------------
// Kernel 1 v2: GEMM1 (logits) + token norm + softmax + a' transpose + asum.
// 1 wave per block, 16 tokens. Grid = 64 n x 37 tb = 2368 blocks.
// Barrier-free K loop: B-frags = b128 direct from ws_w (L2-hot bf16),
// A-side from grids with 1-deep named ping-pong. No LDS for W.
// ---------------------------------------------------------------------------
#define LG2(u0_,u1_, cc_)                                                      \
    if (validA) {                                                              \
        u0_ = *reinterpret_cast<const float4*>(gsrc + (cc_));                  \
        u1_ = *reinterpret_cast<const float4*>(gsrc + (cc_) + 4);              \
    } else {                                                                   \
        u0_ = make_float4(0.f,0.f,0.f,0.f);                                    \
        u1_ = make_float4(0.f,0.f,0.f,0.f);                                    \
    }

#define LW2(b0_,b1_,b2_,b3_, cc_)                                              \
    b0_ = *reinterpret_cast<const bf16x8*>(wbase +            (cc_));          \
    b1_ = *reinterpret_cast<const bf16x8*>(wbase + 16*CCH +   (cc_));          \
    b2_ = *reinterpret_cast<const bf16x8*>(wbase + 32*CCH +   (cc_));          \
    b3_ = *reinterpret_cast<const bf16x8*>(wbase + 48*CCH +   (cc_));

#define STEP2(u0_,u1_, b0_,b1_,b2_,b3_)                                        \
    {                                                                          \
        ss = fmaf(u0_.x,u0_.x, fmaf(u0_.y,u0_.y, fmaf(u0_.z,u0_.z,             \
             fmaf(u0_.w,u0_.w, fmaf(u1_.x,u1_.x, fmaf(u1_.y,u1_.y,             \
             fmaf(u1_.z,u1_.z, fmaf(u1_.w,u1_.w, ss))))))));                   \
        bf16x8 afrag;                                                          \
        ((unsigned short*)&afrag)[0] = f2bf(u0_.x);                            \
        ((unsigned short*)&afrag)[1] = f2bf(u0_.y);                            \
        ((unsigned short*)&afrag)[2] = f2bf(u0_.z);                            \
        ((unsigned short*)&afrag)[3] = f2bf(u0_.w);                            \
        ((unsigned short*)&afrag)[4] = f2bf(u1_.x);                            \
        ((unsigned short*)&afrag)[5] = f2bf(u1_.y);                            \
        ((unsigned short*)&afrag)[6] = f2bf(u1_.z);                            \
        ((unsigned short*)&afrag)[7] = f2bf(u1_.w);                            \
        acc[0] = __builtin_amdgcn_mfma_f32_16x16x32_bf16(afrag, b0_, acc[0], 0, 0, 0); \
        acc[1] = __builtin_amdgcn_mfma_f32_16x16x32_bf16(afrag, b1_, acc[1], 0, 0, 0); \
        acc[2] = __builtin_amdgcn_mfma_f32_16x16x32_bf16(afrag, b2_, acc[2], 0, 0, 0); \
        acc[3] = __builtin_amdgcn_mfma_f32_16x16x32_bf16(afrag, b3_, acc[3], 0, 0, 0); \
    }

__global__ __launch_bounds__(64, 4) void k_logits(
    const float* __restrict__ grids,
    const unsigned short* __restrict__ ws_w,
    const float* __restrict__ conv_b,
    unsigned short* __restrict__ ws_a,
    float* __restrict__ ws_asum)
{
    __shared__ __align__(16) unsigned short Abuf[KR * 24];   // 3 KB

    const int lane = threadIdx.x;
    const int n    = blockIdx.x / TBL;
    const int tbi  = blockIdx.x - n * TBL;
    const int t0w  = tbi << 4;

    const int lr = lane & 15;
    const int lg = lane >> 4;

    const int tokA = t0w + lr;
    const bool validA = (tokA < TT);
    const float* gsrc = grids + ((size_t)n * TT + tokA) * CCH + (lg << 3);
    const unsigned short* wbase = ws_w + (size_t)lr * CCH + (lg << 3);

    f32x4 acc[4] = {};
    float ss = 0.f;

    float4 xa0, xa1, xb0, xb1;
    bf16x8 wa0, wa1, wa2, wa3, wb0, wb1, wb2, wb3;

    LG2(xa0, xa1, 0)
    LW2(wa0, wa1, wa2, wa3, 0)
    #pragma unroll
    for (int cp = 0; cp < 12; ++cp) {
        const int cc = cp << 6;
        LG2(xb0, xb1, cc + 32)
        LW2(wb0, wb1, wb2, wb3, cc + 32)
        STEP2(xa0, xa1, wa0, wa1, wa2, wa3)
        if (cp < 11) {
            LG2(xa0, xa1, cc + 64)
            LW2(wa0, wa1, wa2, wa3, cc + 64)
        }
        STEP2(xb0, xb1, wb0, wb1, wb2, wb3)
    }

    // ---- token norm: reduce over the 4 lg-groups of the same token ----
    ss += __shfl_xor(ss, 16);
    ss += __shfl_xor(ss, 32);
    const float nrm = sqrtf(ss);
    const float inv = 1.0f / fmaxf(nrm, EPSF);

    // ---- logits + softmax over 64 regions ----
    float b_[4];
    #pragma unroll
    for (int rt = 0; rt < 4; ++rt) b_[rt] = conv_b[rt*16 + lr];

    float invT[4];
    #pragma unroll
    for (int reg = 0; reg < 4; ++reg) invT[reg] = __shfl(inv, (lg << 2) + reg);

    float lgt[4][4], mx[4];
    #pragma unroll
    for (int reg = 0; reg < 4; ++reg) {
        float m = -1e30f;
        #pragma unroll
        for (int rt = 0; rt < 4; ++rt) {
            lgt[rt][reg] = fmaf(acc[rt][reg], invT[reg], b_[rt]);
            m = fmaxf(m, lgt[rt][reg]);
        }
        mx[reg] = m;
    }
    #pragma unroll
    for (int msk = 1; msk < 16; msk <<= 1) {
        #pragma unroll
        for (int reg = 0; reg < 4; ++reg) mx[reg] = fmaxf(mx[reg], __shfl_xor(mx[reg], msk));
    }
    float ex[4][4], sm[4] = {0.f, 0.f, 0.f, 0.f};
    #pragma unroll
    for (int rt = 0; rt < 4; ++rt) {
        #pragma unroll
        for (int reg = 0; reg < 4; ++reg) {
            ex[rt][reg] = __expf(lgt[rt][reg] - mx[reg]);
            sm[reg] += ex[rt][reg];
        }
    }
    #pragma unroll
    for (int msk = 1; msk < 16; msk <<= 1) {
        #pragma unroll
        for (int reg = 0; reg < 4; ++reg) sm[reg] += __shfl_xor(sm[reg], msk);
    }

    float rsm[4];
    #pragma unroll
    for (int reg = 0; reg < 4; ++reg) {
        const bool vt = (t0w + (lg << 2) + reg) < TT;
        rsm[reg] = vt ? (1.0f / sm[reg]) : 0.f;
    }

    // ---- per-block (= per-wave) partial asum: kr = rt*16 + lr ----
    float pa[4];
    #pragma unroll
    for (int rt = 0; rt < 4; ++rt) {
        pa[rt] = ex[rt][0]*rsm[0] + ex[rt][1]*rsm[1] + ex[rt][2]*rsm[2] + ex[rt][3]*rsm[3];
        pa[rt] += __shfl_xor(pa[rt], 16);
        pa[rt] += __shfl_xor(pa[rt], 32);
    }
    if (lane < 16) {
        #pragma unroll
        for (int rt = 0; rt < 4; ++rt)
            ws_asum[((size_t)n * TBL + tbi) * 64 + rt*16 + lane] = pa[rt];
    }

    // ---- a' = softmax * inv_norm, transposed via LDS to [kr][t] ----
    #pragma unroll
    for (int reg = 0; reg < 4; ++reg) {
        const int trow = (lg << 2) + reg;
        const float scale = invT[reg] * rsm[reg];
        #pragma unroll
        for (int rt = 0; rt < 4; ++rt)
            Abuf[(rt*16 + lr)*24 + trow] = f2bf(ex[rt][reg] * scale);
    }
    __syncthreads();

    {
        ushort8 r0 = *reinterpret_cast<const ushort8*>(&Abuf[lane * 24]);
        ushort8 r1 = *reinterpret_cast<const ushort8*>(&Abuf[lane * 24 + 8]);
        unsigned short* dst = ws_a + ((size_t)n * KR + lane) * TP + t0w;
        *reinterpret_cast<ushort8*>(dst)     = r0;
        *reinterpret_cast<ushort8*>(dst + 8) = r1;
    }
}

// ---------------------------------------------------------------------------
// Kernel 2: GEMM2 (VLAD): grid = n x 12 c-tiles (64 c) = 768 blocks, 4 waves,
// wave tile 64kr x 16c. Named-variable ping-pong prefetch, fp32 B gathers.
// ---------------------------------------------------------------------------
#define LOADA(d0,d1,d2,d3,t0_)                                                   \
    d0 = *reinterpret_cast<const bf16x8*>(abase +           (size_t)(t0_));      \
    d1 = *reinterpret_cast<const bf16x8*>(abase + 16*TP +   (size_t)(t0_));      \
    d2 = *reinterpret_cast<const bf16x8*>(abase + 32*TP +   (size_t)(t0_));      \
    d3 = *reinterpret_cast<const bf16x8*>(abase + 48*TP +   (size_t)(t0_));

#define LOADB(d,t0_) do {                                                        \
    const int tb2_ = (t0_) + (lg << 3);                                          \
    if ((t0_) + 32 <= TT) {                                                      \
        _Pragma("unroll")                                                        \
        for (int j_ = 0; j_ < 8; ++j_)                                           \
            ((unsigned short*)&(d))[j_] = f2bf(gb[(size_t)(tb2_ + j_) * CCH]);   \
    } else {                                                                     \
        _Pragma("unroll")                                                        \
        for (int j_ = 0; j_ < 8; ++j_) {                                         \
            float v_ = (tb2_ + j_ < TT) ? gb[(size_t)(tb2_ + j_) * CCH] : 0.f;   \
            ((unsigned short*)&(d))[j_] = f2bf(v_);                              \
        }                                                                        \
    } } while (0)

__global__ __launch_bounds__(256, 4) void k_vlad(
    const float* __restrict__ grids,
    const unsigned short* __restrict__ ws_a,
    const float* __restrict__ ws_asum,
    const float* __restrict__ centroids,
    float* __restrict__ out)
{
    __shared__ float asum_s[64];

    const int tid  = threadIdx.x;
    const int lane = tid & 63;
    const int w    = tid >> 6;
    const int n    = blockIdx.x / 12;
    const int c0   = (blockIdx.x - n * 12) << 6;
    const int lr   = lane & 15;
    const int lg   = lane >> 4;

    if (tid < 64) {
        float s = 0.f;
        for (int b = 0; b < TBL; ++b)
            s += ws_asum[((size_t)n * TBL + b) * 64 + tid];
        asum_s[tid] = s;
    }
    __syncthreads();

    const int c = c0 + (w << 4) + lr;
    const unsigned short* abase = ws_a + ((size_t)n * KR + lr) * TP + (lg << 3);
    const float* gb = grids + (size_t)n * TT * CCH + c;

    f32x4 acc0 = {}, acc1 = {}, acc2 = {}, acc3 = {};
    bf16x8 a0, a1, a2, a3, b0;
    bf16x8 p0, p1, p2, p3, q0;

    LOADA(a0, a1, a2, a3, 0)
    LOADB(b0, 0);

    int t0 = 0;
    while (true) {
        int tn = t0 + 32;
        if (tn < TT) { LOADA(p0, p1, p2, p3, tn) LOADB(q0, tn); }
        acc0 = __builtin_amdgcn_mfma_f32_16x16x32_bf16(a0, b0, acc0, 0, 0, 0);
        acc1 = __builtin_amdgcn_mfma_f32_16x16x32_bf16(a1, b0, acc1, 0, 0, 0);
        acc2 = __builtin_amdgcn_mfma_f32_16x16x32_bf16(a2, b0, acc2, 0, 0, 0);
        acc3 = __builtin_amdgcn_mfma_f32_16x16x32_bf16(a3, b0, acc3, 0, 0, 0);
        t0 = tn;
        if (t0 >= TT) break;

        tn = t0 + 32;
        if (tn < TT) { LOADA(a0, a1, a2, a3, tn) LOADB(b0, tn); }
        acc0 = __builtin_amdgcn_mfma_f32_16x16x32_bf16(p0, q0, acc0, 0, 0, 0);
        acc1 = __builtin_amdgcn_mfma_f32_16x16x32_bf16(p1, q0, acc1, 0, 0, 0);
        acc2 = __builtin_amdgcn_mfma_f32_16x16x32_bf16(p2, q0, acc2, 0, 0, 0);
        acc3 = __builtin_amdgcn_mfma_f32_16x16x32_bf16(p3, q0, acc3, 0, 0, 0);
        t0 = tn;
        if (t0 >= TT) break;
    }

    // ---- epilogue: subtract asum*centroid, write fp32 ----
    #pragma unroll
    for (int reg = 0; reg < 4; ++reg) {
        {
            const int kr = 0*16 + (lg << 2) + reg;
            out[((size_t)n * KR + kr) * CCH + c] =
                acc0[reg] - asum_s[kr] * centroids[(size_t)kr * CCH + c];
        }
        {
            const int kr = 1*16 + (lg << 2) + reg;
            out[((size_t)n * KR + kr) * CCH + c] =
                acc1[reg] - asum_s[kr] * centroids[(size_t)kr * CCH + c];
        }
        {
            const int kr = 2*16 + (lg << 2) + reg;
            out[((size_t)n * KR + kr) * CCH + c] =
                acc2[reg] - asum_s[kr] * centroids[(size_t)kr * CCH + c];
        }
        {
            const int kr = 3*16 + (lg << 2) + reg;
            out[((size_t)n * KR + kr) * CCH + c] =
                acc3[reg] - asum_s[kr] * centroids[(size_t)kr * CCH + c];
        }
    }
}

// ---------------------------------------------------------------------------
// Kernel 3: 4 rows per 256-thr block; each wave normalizes one (n,kr) row;
// global L2 norm of 64 unit rows = 8 exactly.
// ---------------------------------------------------------------------------
__global__ __launch_bounds__(256) void kc_norm_kernel(float* __restrict__ out)
{
    const int tid = threadIdx.x;
    const int sub = tid >> 6;
    const int l   = tid & 63;
    float4* p = reinterpret_cast<float4*>(out) + ((size_t)blockIdx.x * 4 + sub) * 192;
    float4 v0 = p[l];
    float4 v1 = p[l + 64];
    float4 v2 = p[l + 128];
    float ss = v0.x*v0.x + v0.y*v0.y + v0.z*v0.z + v0.w*v0.w
             + v1.x*v1.x + v1.y*v1.y + v1.z*v1.z + v1.w*v1.w
             + v2.x*v2.x + v2.y*v2.y + v2.z*v2.z + v2.w*v2.w;
    #pragma unroll
    for (int m = 1; m < 64; m <<= 1) ss += __shfl_xor(ss, m);
    const float sc = 0.125f / fmaxf(sqrtf(ss), EPSF);
    v0.x*=sc; v0.y*=sc; v0.z*=sc; v0.w*=sc;
    v1.x*=sc; v1.y*=sc; v1.z*=sc; v1.w*=sc;
    v2.x*=sc; v2.y*=sc; v2.z*=sc; v2.w*=sc;
    p[l] = v0;
    p[l + 64] = v1;
    p[l + 128] = v2;
}

extern "C" void kernel_launch(void* const* d_in, const int* in_sizes, int n_in,
                              void* d_out, int out_size, void* d_ws, size_t ws_size,
                              hipStream_t stream)
{
    const float* grids     = (const float*)d_in[0];
    const float* conv_w    = (const float*)d_in[1];
    const float* conv_b    = (const float*)d_in[2];
    const float* centroids = (const float*)d_in[3];
    float* out = (float*)d_out;

    // ws layout (bytes):
    //   ws_a    [0,         5,242,880)   64*64*640 bf16
    //   ws_asum [5,242,880, 5,849,088)   64*37*64 f32 (606,208 B)
    //   ws_w    [5,849,088, 5,947,392)   64*768 bf16 (98,304 B)
    unsigned short* ws_a    = (unsigned short*)d_ws;
    float*          ws_asum = (float*)((char*)d_ws + 5242880);
    unsigned short* ws_w    = (unsigned short*)((char*)d_ws + 5849088);

    hipLaunchKernelGGL(k_prep, dim3(64), dim3(256), 0, stream,
                       conv_w, ws_w, ws_a);
    hipLaunchKernelGGL(k_logits, dim3(NB * TBL), dim3(64), 0, stream,
                       grids, ws_w, conv_b, ws_a, ws_asum);
    hipLaunchKernelGGL(k_vlad, dim3(NB * 12), dim3(256), 0, stream,
                       grids, ws_a, ws_asum, centroids, out);
    hipLaunchKernelGGL(kc_norm_kernel, dim3(NB * KR / 4), dim3(256), 0, stream, out);
}

// Round 10
// 85.234 us; speedup vs baseline: 1.6138x; 1.6138x over previous
//
#include <hip/hip_runtime.h>
#include <hip/hip_bf16.h>
#include <math.h>

#define TT 577          // real tokens per n
#define TP 640          // padded tokens per n
#define CCH 768         // channels
#define KR 64           // regions
#define NB 64           // batch
#define LSTR 136        // LDS row stride in ushorts (272 B = 17 x 16B slots)

typedef __attribute__((ext_vector_type(8))) short bf16x8;
typedef __attribute__((ext_vector_type(8))) unsigned short ushort8;
typedef __attribute__((ext_vector_type(4))) float f32x4;

static constexpr float EPSF = 1e-12f;

// float -> bf16 bits via HW conversion (RNE)
static __device__ inline unsigned short f2bf(float f) {
    return __bfloat16_as_ushort(__float2bfloat16(f));
}
static __device__ inline float bf2f(unsigned short b) {
    union { unsigned int u; float f; } v; v.u = ((unsigned int)b) << 16;
    return v.f;
}

// ---------------------------------------------------------------------------
// Kernel 0: zero ws_a row tails t in [592,640) (read by k_vlad, never
// written by k_logits). 4096 rows = 64 n x 64 kr.
// ---------------------------------------------------------------------------
__global__ __launch_bounds__(256) void k_prep(unsigned short* __restrict__ ws_a)
{
    const int g = blockIdx.x * 256 + threadIdx.x;   // [0, 4096)
    unsigned short* d = ws_a + (size_t)g * TP + 592;
    ushort8 z = {0,0,0,0,0,0,0,0};
    #pragma unroll
    for (int i = 0; i < 6; ++i)
        *reinterpret_cast<ushort8*>(d + i * 8) = z;
}

// ---------------------------------------------------------------------------
// Kernel 1 v3: GEMM1 (logits) + token norm + softmax + a' transpose + asum.
// Grid: 64 n x 10 t-blocks of 64 tokens; 256 thr = 4 waves x 16 tokens.
// Per 128-ch chunk: grids AND conv_w staged COALESCED into LDS (fp32->bf16,
// row stride 272 B), double-buffered, 1 barrier/chunk, T14 ordering
// (issue loads -> compute -> LDS-write -> barrier). MFMA frags from LDS.
// This kills the 16-scattered-line-per-load pattern that capped R1-R9 at
// ~1.7 TB/s effective (VMEM line-queue bound).
// ---------------------------------------------------------------------------

// stage one 128-ch chunk of grids (64 tok) or W (64 kr) into regs: 4 units
// of (row, 8 ch) per thread; unit u = it*256+tid -> row=u>>4, slot=u&15.
#define STAGE_G(c0_)                                                           \
    {                                                                          \
        _Pragma("unroll")                                                      \
        for (int it = 0; it < 4; ++it) {                                       \
            const int u  = (it << 8) + tid;                                    \
            const int tk = u >> 4, sl = u & 15;                                \
            if (tb + tk < TT) {                                                \
                const float* s_ = grids + ((size_t)n * TT + tb + tk) * CCH     \
                                  + (c0_) + (sl << 3);                         \
                gr[it][0] = *reinterpret_cast<const float4*>(s_);              \
                gr[it][1] = *reinterpret_cast<const float4*>(s_ + 4);          \
            } else {                                                           \
                gr[it][0] = make_float4(0.f,0.f,0.f,0.f);                      \
                gr[it][1] = make_float4(0.f,0.f,0.f,0.f);                      \
            }                                                                  \
        }                                                                      \
    }

#define STAGE_W(c0_)                                                           \
    {                                                                          \
        _Pragma("unroll")                                                      \
        for (int it = 0; it < 4; ++it) {                                       \
            const int u  = (it << 8) + tid;                                    \
            const int kr = u >> 4, sl = u & 15;                                \
            const float* s_ = conv_w + (size_t)kr * CCH + (c0_) + (sl << 3);   \
            wr[it][0] = *reinterpret_cast<const float4*>(s_);                  \
            wr[it][1] = *reinterpret_cast<const float4*>(s_ + 4);              \
        }                                                                      \
    }

#define CVT8(dst_, a_, b_)                                                     \
    { dst_[0]=f2bf(a_.x); dst_[1]=f2bf(a_.y); dst_[2]=f2bf(a_.z);              \
      dst_[3]=f2bf(a_.w); dst_[4]=f2bf(b_.x); dst_[5]=f2bf(b_.y);              \
      dst_[6]=f2bf(b_.z); dst_[7]=f2bf(b_.w); }

#define WRITE_G(buf_)                                                          \
    {                                                                          \
        _Pragma("unroll")                                                      \
        for (int it = 0; it < 4; ++it) {                                       \
            const int u  = (it << 8) + tid;                                    \
            const int tk = u >> 4, sl = u & 15;                                \
            ushort8 o;                                                         \
            CVT8(o, gr[it][0], gr[it][1])                                      \
            *reinterpret_cast<ushort8*>(&Gs[buf_][tk * LSTR + (sl << 3)]) = o; \
        }                                                                      \
    }

#define WRITE_W(buf_)                                                          \
    {                                                                          \
        _Pragma("unroll")                                                      \
        for (int it = 0; it < 4; ++it) {                                       \
            const int u  = (it << 8) + tid;                                    \
            const int kr = u >> 4, sl = u & 15;                                \
            ushort8 o;                                                         \
            CVT8(o, wr[it][0], wr[it][1])                                      \
            *reinterpret_cast<ushort8*>(&Ws[buf_][kr * LSTR + (sl << 3)]) = o; \
        }                                                                      \
    }

// one 32-ch K-step s_ from LDS buffer buf_
#define KSTEP(buf_, s_)                                                        \
    {                                                                          \
        bf16x8 af = *reinterpret_cast<const bf16x8*>(                          \
            &Gs[buf_][((w << 4) + lr) * LSTR + ((((s_) << 2) + lg) << 3)]);    \
        _Pragma("unroll")                                                      \
        for (int j = 0; j < 8; ++j) {                                          \
            const float v_ = bf2f(((unsigned short*)&af)[j]);                  \
            ss = fmaf(v_, v_, ss);                                             \
        }                                                                      \
        const int csl = (((s_) << 2) + lg) << 3;                               \
        bf16x8 b0_ = *reinterpret_cast<const bf16x8*>(&Ws[buf_][ lr       * LSTR + csl]); \
        bf16x8 b1_ = *reinterpret_cast<const bf16x8*>(&Ws[buf_][(16 + lr) * LSTR + csl]); \
        bf16x8 b2_ = *reinterpret_cast<const bf16x8*>(&Ws[buf_][(32 + lr) * LSTR + csl]); \
        bf16x8 b3_ = *reinterpret_cast<const bf16x8*>(&Ws[buf_][(48 + lr) * LSTR + csl]); \
        acc[0] = __builtin_amdgcn_mfma_f32_16x16x32_bf16(af, b0_, acc[0], 0, 0, 0); \
        acc[1] = __builtin_amdgcn_mfma_f32_16x16x32_bf16(af, b1_, acc[1], 0, 0, 0); \
        acc[2] = __builtin_amdgcn_mfma_f32_16x16x32_bf16(af, b2_, acc[2], 0, 0, 0); \
        acc[3] = __builtin_amdgcn_mfma_f32_16x16x32_bf16(af, b3_, acc[3], 0, 0, 0); \
    }

__global__ __launch_bounds__(256, 2) void k_logits(
    const float* __restrict__ grids,
    const float* __restrict__ conv_w,
    const float* __restrict__ conv_b,
    unsigned short* __restrict__ ws_a,
    float* __restrict__ ws_asum)
{
    __shared__ __align__(16) unsigned short Gs[2][64 * LSTR];  // 2 x 17.4 KB
    __shared__ __align__(16) unsigned short Ws[2][64 * LSTR];  // 2 x 17.4 KB
    __shared__ float asum_lds[4][64];                          // 1 KB

    const int tid  = threadIdx.x;
    const int lane = tid & 63;
    const int w    = tid >> 6;
    const int n    = blockIdx.x / 10;
    const int tb   = (blockIdx.x - n * 10) << 6;
    const int t0w  = tb + (w << 4);

    const int lr = lane & 15;
    const int lg = lane >> 4;

    float4 gr[4][2], wr[4][2];
    f32x4 acc[4] = {};
    float ss = 0.f;

    STAGE_G(0) STAGE_W(0)
    WRITE_G(0) WRITE_W(0)
    __syncthreads();

    #pragma unroll
    for (int ch = 0; ch < 6; ++ch) {
        const int buf = ch & 1;
        if (ch < 5) { STAGE_G((ch + 1) << 7) STAGE_W((ch + 1) << 7) }
        KSTEP(buf, 0) KSTEP(buf, 1) KSTEP(buf, 2) KSTEP(buf, 3)
        if (ch < 5) { WRITE_G(buf ^ 1) WRITE_W(buf ^ 1) }
        __syncthreads();
    }

    // ---- token norm: reduce over the 4 lg-groups of the same token ----
    ss += __shfl_xor(ss, 16);
    ss += __shfl_xor(ss, 32);
    const float nrm = sqrtf(ss);
    const float inv = 1.0f / fmaxf(nrm, EPSF);

    // ---- logits + softmax over 64 regions ----
    float b_[4];
    #pragma unroll
    for (int rt = 0; rt < 4; ++rt) b_[rt] = conv_b[rt*16 + lr];

    float invT[4];
    #pragma unroll
    for (int reg = 0; reg < 4; ++reg) invT[reg] = __shfl(inv, (lg << 2) + reg);

    float lgt[4][4], mx[4];
    #pragma unroll
    for (int reg = 0; reg < 4; ++reg) {
        float m = -1e30f;
        #pragma unroll
        for (int rt = 0; rt < 4; ++rt) {
            lgt[rt][reg] = fmaf(acc[rt][reg], invT[reg], b_[rt]);
            m = fmaxf(m, lgt[rt][reg]);
        }
        mx[reg] = m;
    }
    #pragma unroll
    for (int msk = 1; msk < 16; msk <<= 1) {
        #pragma unroll
        for (int reg = 0; reg < 4; ++reg) mx[reg] = fmaxf(mx[reg], __shfl_xor(mx[reg], msk));
    }
    float ex[4][4], sm[4] = {0.f, 0.f, 0.f, 0.f};
    #pragma unroll
    for (int rt = 0; rt < 4; ++rt) {
        #pragma unroll
        for (int reg = 0; reg < 4; ++reg) {
            ex[rt][reg] = __expf(lgt[rt][reg] - mx[reg]);
            sm[reg] += ex[rt][reg];
        }
    }
    #pragma unroll
    for (int msk = 1; msk < 16; msk <<= 1) {
        #pragma unroll
        for (int reg = 0; reg < 4; ++reg) sm[reg] += __shfl_xor(sm[reg], msk);
    }

    float rsm[4];
    #pragma unroll
    for (int reg = 0; reg < 4; ++reg) {
        const bool vt = (t0w + (lg << 2) + reg) < TT;
        rsm[reg] = vt ? (1.0f / sm[reg]) : 0.f;
    }

    // ---- per-block partial asum: pa[rt] holds kr = rt*16+lr ----
    float pa[4];
    #pragma unroll
    for (int rt = 0; rt < 4; ++rt) {
        pa[rt] = ex[rt][0]*rsm[0] + ex[rt][1]*rsm[1] + ex[rt][2]*rsm[2] + ex[rt][3]*rsm[3];
        pa[rt] += __shfl_xor(pa[rt], 16);
        pa[rt] += __shfl_xor(pa[rt], 32);
    }
    if (lane < 16) {
        #pragma unroll
        for (int rt = 0; rt < 4; ++rt)
            asum_lds[w][rt*16 + lane] = pa[rt];
    }

    // ---- a' = softmax*inv_norm, transposed via wave-private LDS region
    //      (aliased onto Gs[0]; last compute chunk used Gs[1]) ----
    unsigned short* Abuf = &Gs[0][0] + (size_t)w * KR * 24;
    #pragma unroll
    for (int reg = 0; reg < 4; ++reg) {
        const int trow = (lg << 2) + reg;
        const float scale = invT[reg] * rsm[reg];
        #pragma unroll
        for (int rt = 0; rt < 4; ++rt)
            Abuf[(rt*16 + lr)*24 + trow] = f2bf(ex[rt][reg] * scale);
    }
    __syncthreads();

    if (tid < 64)
        ws_asum[(size_t)blockIdx.x * 64 + tid] =
            asum_lds[0][tid] + asum_lds[1][tid] + asum_lds[2][tid] + asum_lds[3][tid];

    {
        ushort8 r0 = *reinterpret_cast<const ushort8*>(&Abuf[lane * 24]);
        ushort8 r1 = *reinterpret_cast<const ushort8*>(&Abuf[lane * 24 + 8]);
        unsigned short* dst = ws_a + ((size_t)n * KR + lane) * TP + t0w;
        *reinterpret_cast<ushort8*>(dst)     = r0;
        *reinterpret_cast<ushort8*>(dst + 8) = r1;
    }
}

// ---------------------------------------------------------------------------
// Kernel 2: GEMM2 (VLAD): unchanged from R8 (proven). grid = n x 12 c-tiles.
// ---------------------------------------------------------------------------
#define LOADA(d0,d1,d2,d3,t0_)                                                   \
    d0 = *reinterpret_cast<const bf16x8*>(abase +           (size_t)(t0_));      \
    d1 = *reinterpret_cast<const bf16x8*>(abase + 16*TP +   (size_t)(t0_));      \
    d2 = *reinterpret_cast<const bf16x8*>(abase + 32*TP +   (size_t)(t0_));      \
    d3 = *reinterpret_cast<const bf16x8*>(abase + 48*TP +   (size_t)(t0_));

#define LOADB(d,t0_) do {                                                        \
    const int tb2_ = (t0_) + (lg << 3);                                          \
    if ((t0_) + 32 <= TT) {                                                      \
        _Pragma("unroll")                                                        \
        for (int j_ = 0; j_ < 8; ++j_)                                           \
            ((unsigned short*)&(d))[j_] = f2bf(gb[(size_t)(tb2_ + j_) * CCH]);   \
    } else {                                                                     \
        _Pragma("unroll")                                                        \
        for (int j_ = 0; j_ < 8; ++j_) {                                         \
            float v_ = (tb2_ + j_ < TT) ? gb[(size_t)(tb2_ + j_) * CCH] : 0.f;   \
            ((unsigned short*)&(d))[j_] = f2bf(v_);                              \
        }                                                                        \
    } } while (0)

__global__ __launch_bounds__(256, 4) void k_vlad(
    const float* __restrict__ grids,
    const unsigned short* __restrict__ ws_a,
    const float* __restrict__ ws_asum,
    const float* __restrict__ centroids,
    float* __restrict__ out)
{
    __shared__ float asum_s[64];

    const int tid  = threadIdx.x;
    const int lane = tid & 63;
    const int w    = tid >> 6;
    const int n    = blockIdx.x / 12;
    const int c0   = (blockIdx.x - n * 12) << 6;
    const int lr   = lane & 15;
    const int lg   = lane >> 4;

    if (tid < 64) {
        float s = 0.f;
        #pragma unroll
        for (int b = 0; b < 10; ++b)
            s += ws_asum[((size_t)n * 10 + b) * 64 + tid];
        asum_s[tid] = s;
    }
    __syncthreads();

    const int c = c0 + (w << 4) + lr;
    const unsigned short* abase = ws_a + ((size_t)n * KR + lr) * TP + (lg << 3);
    const float* gb = grids + (size_t)n * TT * CCH + c;

    f32x4 acc0 = {}, acc1 = {}, acc2 = {}, acc3 = {};
    bf16x8 a0, a1, a2, a3, b0;
    bf16x8 p0, p1, p2, p3, q0;

    LOADA(a0, a1, a2, a3, 0)
    LOADB(b0, 0);

    int t0 = 0;
    while (true) {
        int tn = t0 + 32;
        if (tn < TT) { LOADA(p0, p1, p2, p3, tn) LOADB(q0, tn); }
        acc0 = __builtin_amdgcn_mfma_f32_16x16x32_bf16(a0, b0, acc0, 0, 0, 0);
        acc1 = __builtin_amdgcn_mfma_f32_16x16x32_bf16(a1, b0, acc1, 0, 0, 0);
        acc2 = __builtin_amdgcn_mfma_f32_16x16x32_bf16(a2, b0, acc2, 0, 0, 0);
        acc3 = __builtin_amdgcn_mfma_f32_16x16x32_bf16(a3, b0, acc3, 0, 0, 0);
        t0 = tn;
        if (t0 >= TT) break;

        tn = t0 + 32;
        if (tn < TT) { LOADA(a0, a1, a2, a3, tn) LOADB(b0, tn); }
        acc0 = __builtin_amdgcn_mfma_f32_16x16x32_bf16(p0, q0, acc0, 0, 0, 0);
        acc1 = __builtin_amdgcn_mfma_f32_16x16x32_bf16(p1, q0, acc1, 0, 0, 0);
        acc2 = __builtin_amdgcn_mfma_f32_16x16x32_bf16(p2, q0, acc2, 0, 0, 0);
        acc3 = __builtin_amdgcn_mfma_f32_16x16x32_bf16(p3, q0, acc3, 0, 0, 0);
        t0 = tn;
        if (t0 >= TT) break;
    }

    #pragma unroll
    for (int reg = 0; reg < 4; ++reg) {
        {
            const int kr = 0*16 + (lg << 2) + reg;
            out[((size_t)n * KR + kr) * CCH + c] =
                acc0[reg] - asum_s[kr] * centroids[(size_t)kr * CCH + c];
        }
        {
            const int kr = 1*16 + (lg << 2) + reg;
            out[((size_t)n * KR + kr) * CCH + c] =
                acc1[reg] - asum_s[kr] * centroids[(size_t)kr * CCH + c];
        }
        {
            const int kr = 2*16 + (lg << 2) + reg;
            out[((size_t)n * KR + kr) * CCH + c] =
                acc2[reg] - asum_s[kr] * centroids[(size_t)kr * CCH + c];
        }
        {
            const int kr = 3*16 + (lg << 2) + reg;
            out[((size_t)n * KR + kr) * CCH + c] =
                acc3[reg] - asum_s[kr] * centroids[(size_t)kr * CCH + c];
        }
    }
}

// ---------------------------------------------------------------------------
// Kernel 3: 4 rows per 256-thr block; global L2 norm of 64 unit rows = 8.
// ---------------------------------------------------------------------------
__global__ __launch_bounds__(256) void kc_norm_kernel(float* __restrict__ out)
{
    const int tid = threadIdx.x;
    const int sub = tid >> 6;
    const int l   = tid & 63;
    float4* p = reinterpret_cast<float4*>(out) + ((size_t)blockIdx.x * 4 + sub) * 192;
    float4 v0 = p[l];
    float4 v1 = p[l + 64];
    float4 v2 = p[l + 128];
    float ss = v0.x*v0.x + v0.y*v0.y + v0.z*v0.z + v0.w*v0.w
             + v1.x*v1.x + v1.y*v1.y + v1.z*v1.z + v1.w*v1.w
             + v2.x*v2.x + v2.y*v2.y + v2.z*v2.z + v2.w*v2.w;
    #pragma unroll
    for (int m = 1; m < 64; m <<= 1) ss += __shfl_xor(ss, m);
    const float sc = 0.125f / fmaxf(sqrtf(ss), EPSF);
    v0.x*=sc; v0.y*=sc; v0.z*=sc; v0.w*=sc;
    v1.x*=sc; v1.y*=sc; v1.z*=sc; v1.w*=sc;
    v2.x*=sc; v2.y*=sc; v2.z*=sc; v2.w*=sc;
    p[l] = v0;
    p[l + 64] = v1;
    p[l + 128] = v2;
}

extern "C" void kernel_launch(void* const* d_in, const int* in_sizes, int n_in,
                              void* d_out, int out_size, void* d_ws, size_t ws_size,
                              hipStream_t stream)
{
    const float* grids     = (const float*)d_in[0];
    const float* conv_w    = (const float*)d_in[1];
    const float* conv_b    = (const float*)d_in[2];
    const float* centroids = (const float*)d_in[3];
    float* out = (float*)d_out;

    // ws layout (bytes):
    //   ws_a    [0,         5,242,880)   64*64*640 bf16
    //   ws_asum [5,242,880, 5,406,720)   640*64 f32
    unsigned short* ws_a    = (unsigned short*)d_ws;
    float*          ws_asum = (float*)((char*)d_ws + 5242880);

    hipLaunchKernelGGL(k_prep, dim3(16), dim3(256), 0, stream, ws_a);
    hipLaunchKernelGGL(k_logits, dim3(NB * 10), dim3(256), 0, stream,
                       grids, conv_w, conv_b, ws_a, ws_asum);
    hipLaunchKernelGGL(k_vlad, dim3(NB * 12), dim3(256), 0, stream,
                       grids, ws_a, ws_asum, centroids, out);
    hipLaunchKernelGGL(kc_norm_kernel, dim3(NB * KR / 4), dim3(256), 0, stream, out);
}

// Round 11
// 74.206 us; speedup vs baseline: 1.8537x; 1.1486x over previous
//
#include <hip/hip_runtime.h>
#include <hip/hip_bf16.h>
#include <math.h>

#define TT 577          // real tokens per n
#define TP 640          // padded tokens per n
#define CCH 768         // channels
#define KR 64           // regions
#define NB 64           // batch

typedef __attribute__((ext_vector_type(8))) short bf16x8;
typedef __attribute__((ext_vector_type(8))) unsigned short ushort8;
typedef __attribute__((ext_vector_type(4))) float f32x4;

static constexpr float EPSF = 1e-12f;

// float -> bf16 bits via HW conversion (RNE)
static __device__ inline unsigned short f2bf(float f) {
    return __bfloat16_as_ushort(__float2bfloat16(f));
}

// ---------------------------------------------------------------------------
// Kernel 0: one-time prep. (a) conv_w fp32 -> bf16 ws_w[64][768];
// (b) zero ws_a row tails t in [592,640). Grid 24 x 256.
// ---------------------------------------------------------------------------
__global__ __launch_bounds__(256) void k_prep(
    const float* __restrict__ conv_w,
    unsigned short* __restrict__ ws_w,
    unsigned short* __restrict__ ws_a)
{
    const int g = blockIdx.x * 256 + threadIdx.x;   // [0, 6144)
    if (g < 6144) {                                 // 6144 * 8 = 49152 = 64*768
        const float* s = conv_w + (size_t)g * 8;
        float4 v0 = *reinterpret_cast<const float4*>(s);
        float4 v1 = *reinterpret_cast<const float4*>(s + 4);
        ushort8 o;
        o[0]=f2bf(v0.x); o[1]=f2bf(v0.y); o[2]=f2bf(v0.z); o[3]=f2bf(v0.w);
        o[4]=f2bf(v1.x); o[5]=f2bf(v1.y); o[6]=f2bf(v1.z); o[7]=f2bf(v1.w);
        *reinterpret_cast<ushort8*>(ws_w + (size_t)g * 8) = o;
    }
    if (g < 4096) {                                 // 4096 rows = 64 n * 64 kr
        unsigned short* d = ws_a + (size_t)g * TP + 592;
        ushort8 z = {0,0,0,0,0,0,0,0};
        #pragma unroll
        for (int i = 0; i < 6; ++i)
            *reinterpret_cast<ushort8*>(d + i * 8) = z;
    }
}

// ---------------------------------------------------------------------------
// Kernel 1 v4 (= R8 structure + bf16-W + T14): GEMM1 + norm + softmax +
// a' transpose + partial asum. Grid: 64 n x 10 t-blocks; 256 thr = 4 waves.
// W (bf16, prepped) double-buffered in LDS, 1 barrier/chunk, T14 order:
// issue W loads -> compute s-loop -> ds_write W -> barrier.
// grids read per-lane direct (empirically best across R4-R10).
// ---------------------------------------------------------------------------
__global__ __launch_bounds__(256, 3) void k_logits(
    const float* __restrict__ grids,
    const unsigned short* __restrict__ ws_w,
    const float* __restrict__ conv_b,
    unsigned short* __restrict__ ws_a,
    float* __restrict__ ws_asum)
{
    __shared__ __align__(16) unsigned short Wl[2][KR * 136];   // 2 x 17.4 KB
    __shared__ float asum_lds[4][64];                          // 1 KB

    const int tid  = threadIdx.x;
    const int lane = tid & 63;
    const int w    = tid >> 6;
    const int n    = blockIdx.x / 10;
    const int tb   = (blockIdx.x - n * 10) << 6;
    const int t0w  = tb + (w << 4);

    const int lr = lane & 15;
    const int lg = lane >> 4;

    const int tokA = t0w + lr;
    const bool validA = (tokA < TT);
    const float* gsrc = grids + ((size_t)n * TT + tokA) * CCH + (lg << 3);

    // W chunk = 64 kr x 128 ch bf16 = 1024 ushort8 units; 4 units/thread.
    ushort8 wreg0, wreg1, wreg2, wreg3;
    #define WLOAD(c0_)                                                         \
        {                                                                      \
            const int u0_ = tid,       u1_ = tid + 256,                        \
                      u2_ = tid + 512, u3_ = tid + 768;                        \
            wreg0 = *reinterpret_cast<const ushort8*>(                         \
                ws_w + (size_t)(u0_ >> 4) * CCH + (c0_) + ((u0_ & 15) << 3));  \
            wreg1 = *reinterpret_cast<const ushort8*>(                         \
                ws_w + (size_t)(u1_ >> 4) * CCH + (c0_) + ((u1_ & 15) << 3));  \
            wreg2 = *reinterpret_cast<const ushort8*>(                         \
                ws_w + (size_t)(u2_ >> 4) * CCH + (c0_) + ((u2_ & 15) << 3));  \
            wreg3 = *reinterpret_cast<const ushort8*>(                         \
                ws_w + (size_t)(u3_ >> 4) * CCH + (c0_) + ((u3_ & 15) << 3));  \
        }
    #define WSTORE(buf_)                                                       \
        {                                                                      \
            const int u0_ = tid,       u1_ = tid + 256,                        \
                      u2_ = tid + 512, u3_ = tid + 768;                        \
            *reinterpret_cast<ushort8*>(                                       \
                &Wl[buf_][(u0_ >> 4) * 136 + ((u0_ & 15) << 3)]) = wreg0;      \
            *reinterpret_cast<ushort8*>(                                       \
                &Wl[buf_][(u1_ >> 4) * 136 + ((u1_ & 15) << 3)]) = wreg1;      \
            *reinterpret_cast<ushort8*>(                                       \
                &Wl[buf_][(u2_ >> 4) * 136 + ((u2_ & 15) << 3)]) = wreg2;      \
            *reinterpret_cast<ushort8*>(                                       \
                &Wl[buf_][(u3_ >> 4) * 136 + ((u3_ & 15) << 3)]) = wreg3;      \
        }

    f32x4 acc[4] = {};
    float ss = 0.f;

    WLOAD(0)
    WSTORE(0)
    __syncthreads();

    for (int ch = 0; ch < 6; ++ch) {
        if (ch < 5) WLOAD((ch + 1) << 7)          // T14: issue early
        const int c0 = ch << 7;
        const unsigned short* Wb = Wl[ch & 1];

        #pragma unroll
        for (int s = 0; s < 4; ++s) {
            float a8[8];
            if (validA) {
                float4 u0 = *reinterpret_cast<const float4*>(gsrc + c0 + (s << 5));
                float4 u1 = *reinterpret_cast<const float4*>(gsrc + c0 + (s << 5) + 4);
                a8[0]=u0.x; a8[1]=u0.y; a8[2]=u0.z; a8[3]=u0.w;
                a8[4]=u1.x; a8[5]=u1.y; a8[6]=u1.z; a8[7]=u1.w;
            } else {
                #pragma unroll
                for (int j = 0; j < 8; ++j) a8[j] = 0.f;
            }
            bf16x8 afrag;
            #pragma unroll
            for (int j = 0; j < 8; ++j) {
                ss = fmaf(a8[j], a8[j], ss);
                ((unsigned short*)&afrag)[j] = f2bf(a8[j]);
            }
            const int cl = (s << 5) + (lg << 3);
            #pragma unroll
            for (int rt = 0; rt < 4; ++rt) {
                bf16x8 bfrag = *reinterpret_cast<const bf16x8*>(&Wb[(rt*16 + lr)*136 + cl]);
                acc[rt] = __builtin_amdgcn_mfma_f32_16x16x32_bf16(afrag, bfrag, acc[rt], 0, 0, 0);
            }
        }

        if (ch < 5) WSTORE((ch + 1) & 1)          // T14: write late (other buf)
        __syncthreads();
    }

    // ---- token norm: reduce the 4 lg-groups of the same token ----
    ss += __shfl_xor(ss, 16);
    ss += __shfl_xor(ss, 32);
    const float nrm = sqrtf(ss);
    const float inv = 1.0f / fmaxf(nrm, EPSF);

    // ---- logits + softmax over 64 regions ----
    float b_[4];
    #pragma unroll
    for (int rt = 0; rt < 4; ++rt) b_[rt] = conv_b[rt*16 + lr];

    float invT[4];
    #pragma unroll
    for (int reg = 0; reg < 4; ++reg) invT[reg] = __shfl(inv, (lg << 2) + reg);

    float lgt[4][4], mx[4];
    #pragma unroll
    for (int reg = 0; reg < 4; ++reg) {
        float m = -1e30f;
        #pragma unroll
        for (int rt = 0; rt < 4; ++rt) {
            lgt[rt][reg] = fmaf(acc[rt][reg], invT[reg], b_[rt]);
            m = fmaxf(m, lgt[rt][reg]);
        }
        mx[reg] = m;
    }
    #pragma unroll
    for (int msk = 1; msk < 16; msk <<= 1) {
        #pragma unroll
        for (int reg = 0; reg < 4; ++reg) mx[reg] = fmaxf(mx[reg], __shfl_xor(mx[reg], msk));
    }
    float ex[4][4], sm[4] = {0.f, 0.f, 0.f, 0.f};
    #pragma unroll
    for (int rt = 0; rt < 4; ++rt) {
        #pragma unroll
        for (int reg = 0; reg < 4; ++reg) {
            ex[rt][reg] = __expf(lgt[rt][reg] - mx[reg]);
            sm[reg] += ex[rt][reg];
        }
    }
    #pragma unroll
    for (int msk = 1; msk < 16; msk <<= 1) {
        #pragma unroll
        for (int reg = 0; reg < 4; ++reg) sm[reg] += __shfl_xor(sm[reg], msk);
    }

    float rsm[4];
    #pragma unroll
    for (int reg = 0; reg < 4; ++reg) {
        const bool vt = (t0w + (lg << 2) + reg) < TT;
        rsm[reg] = vt ? (1.0f / sm[reg]) : 0.f;
    }

    // ---- per-block partial asum: pa[rt] holds kr = rt*16+lr ----
    float pa[4];
    #pragma unroll
    for (int rt = 0; rt < 4; ++rt) {
        pa[rt] = ex[rt][0]*rsm[0] + ex[rt][1]*rsm[1] + ex[rt][2]*rsm[2] + ex[rt][3]*rsm[3];
        pa[rt] += __shfl_xor(pa[rt], 16);
        pa[rt] += __shfl_xor(pa[rt], 32);
    }
    if (lane < 16) {
        #pragma unroll
        for (int rt = 0; rt < 4; ++rt)
            asum_lds[w][rt*16 + lane] = pa[rt];
    }

    // ---- a' = softmax * inv_norm, transposed via LDS (aliased on Wl[0]) ----
    unsigned short* Abuf = &Wl[0][0] + (size_t)w * KR * 24;
    #pragma unroll
    for (int reg = 0; reg < 4; ++reg) {
        const int trow = (lg << 2) + reg;
        const float scale = invT[reg] * rsm[reg];
        #pragma unroll
        for (int rt = 0; rt < 4; ++rt)
            Abuf[(rt*16 + lr)*24 + trow] = f2bf(ex[rt][reg] * scale);
    }
    __syncthreads();

    if (tid < 64)
        ws_asum[(size_t)blockIdx.x * 64 + tid] =
            asum_lds[0][tid] + asum_lds[1][tid] + asum_lds[2][tid] + asum_lds[3][tid];

    {
        ushort8 r0 = *reinterpret_cast<const ushort8*>(&Abuf[lane * 24]);
        ushort8 r1 = *reinterpret_cast<const ushort8*>(&Abuf[lane * 24 + 8]);
        unsigned short* dst = ws_a + ((size_t)n * KR + lane) * TP + t0w;
        *reinterpret_cast<ushort8*>(dst)     = r0;
        *reinterpret_cast<ushort8*>(dst + 8) = r1;
    }
}

// ---------------------------------------------------------------------------
// Kernel 2: GEMM2 (VLAD): unchanged from R8 (proven). grid = n x 12 c-tiles.
// ---------------------------------------------------------------------------
#define LOADA(d0,d1,d2,d3,t0_)                                                   \
    d0 = *reinterpret_cast<const bf16x8*>(abase +           (size_t)(t0_));      \
    d1 = *reinterpret_cast<const bf16x8*>(abase + 16*TP +   (size_t)(t0_));      \
    d2 = *reinterpret_cast<const bf16x8*>(abase + 32*TP +   (size_t)(t0_));      \
    d3 = *reinterpret_cast<const bf16x8*>(abase + 48*TP +   (size_t)(t0_));

#define LOADB(d,t0_) do {                                                        \
    const int tb2_ = (t0_) + (lg << 3);                                          \
    if ((t0_) + 32 <= TT) {                                                      \
        _Pragma("unroll")                                                        \
        for (int j_ = 0; j_ < 8; ++j_)                                           \
            ((unsigned short*)&(d))[j_] = f2bf(gb[(size_t)(tb2_ + j_) * CCH]);   \
    } else {                                                                     \
        _Pragma("unroll")                                                        \
        for (int j_ = 0; j_ < 8; ++j_) {                                         \
            float v_ = (tb2_ + j_ < TT) ? gb[(size_t)(tb2_ + j_) * CCH] : 0.f;   \
            ((unsigned short*)&(d))[j_] = f2bf(v_);                              \
        }                                                                        \
    } } while (0)

__global__ __launch_bounds__(256, 4) void k_vlad(
    const float* __restrict__ grids,
    const unsigned short* __restrict__ ws_a,
    const float* __restrict__ ws_asum,
    const float* __restrict__ centroids,
    float* __restrict__ out)
{
    __shared__ float asum_s[64];

    const int tid  = threadIdx.x;
    const int lane = tid & 63;
    const int w    = tid >> 6;
    const int n    = blockIdx.x / 12;
    const int c0   = (blockIdx.x - n * 12) << 6;
    const int lr   = lane & 15;
    const int lg   = lane >> 4;

    if (tid < 64) {
        float s = 0.f;
        #pragma unroll
        for (int b = 0; b < 10; ++b)
            s += ws_asum[((size_t)n * 10 + b) * 64 + tid];
        asum_s[tid] = s;
    }
    __syncthreads();

    const int c = c0 + (w << 4) + lr;
    const unsigned short* abase = ws_a + ((size_t)n * KR + lr) * TP + (lg << 3);
    const float* gb = grids + (size_t)n * TT * CCH + c;

    f32x4 acc0 = {}, acc1 = {}, acc2 = {}, acc3 = {};
    bf16x8 a0, a1, a2, a3, b0;
    bf16x8 p0, p1, p2, p3, q0;

    LOADA(a0, a1, a2, a3, 0)
    LOADB(b0, 0);

    int t0 = 0;
    while (true) {
        int tn = t0 + 32;
        if (tn < TT) { LOADA(p0, p1, p2, p3, tn) LOADB(q0, tn); }
        acc0 = __builtin_amdgcn_mfma_f32_16x16x32_bf16(a0, b0, acc0, 0, 0, 0);
        acc1 = __builtin_amdgcn_mfma_f32_16x16x32_bf16(a1, b0, acc1, 0, 0, 0);
        acc2 = __builtin_amdgcn_mfma_f32_16x16x32_bf16(a2, b0, acc2, 0, 0, 0);
        acc3 = __builtin_amdgcn_mfma_f32_16x16x32_bf16(a3, b0, acc3, 0, 0, 0);
        t0 = tn;
        if (t0 >= TT) break;

        tn = t0 + 32;
        if (tn < TT) { LOADA(a0, a1, a2, a3, tn) LOADB(b0, tn); }
        acc0 = __builtin_amdgcn_mfma_f32_16x16x32_bf16(p0, q0, acc0, 0, 0, 0);
        acc1 = __builtin_amdgcn_mfma_f32_16x16x32_bf16(p1, q0, acc1, 0, 0, 0);
        acc2 = __builtin_amdgcn_mfma_f32_16x16x32_bf16(p2, q0, acc2, 0, 0, 0);
        acc3 = __builtin_amdgcn_mfma_f32_16x16x32_bf16(p3, q0, acc3, 0, 0, 0);
        t0 = tn;
        if (t0 >= TT) break;
    }

    #pragma unroll
    for (int reg = 0; reg < 4; ++reg) {
        {
            const int kr = 0*16 + (lg << 2) + reg;
            out[((size_t)n * KR + kr) * CCH + c] =
                acc0[reg] - asum_s[kr] * centroids[(size_t)kr * CCH + c];
        }
        {
            const int kr = 1*16 + (lg << 2) + reg;
            out[((size_t)n * KR + kr) * CCH + c] =
                acc1[reg] - asum_s[kr] * centroids[(size_t)kr * CCH + c];
        }
        {
            const int kr = 2*16 + (lg << 2) + reg;
            out[((size_t)n * KR + kr) * CCH + c] =
                acc2[reg] - asum_s[kr] * centroids[(size_t)kr * CCH + c];
        }
        {
            const int kr = 3*16 + (lg << 2) + reg;
            out[((size_t)n * KR + kr) * CCH + c] =
                acc3[reg] - asum_s[kr] * centroids[(size_t)kr * CCH + c];
        }
    }
}

// ---------------------------------------------------------------------------
// Kernel 3: 4 rows per 256-thr block; global L2 norm of 64 unit rows = 8.
// ---------------------------------------------------------------------------
__global__ __launch_bounds__(256) void kc_norm_kernel(float* __restrict__ out)
{
    const int tid = threadIdx.x;
    const int sub = tid >> 6;
    const int l   = tid & 63;
    float4* p = reinterpret_cast<float4*>(out) + ((size_t)blockIdx.x * 4 + sub) * 192;
    float4 v0 = p[l];
    float4 v1 = p[l + 64];
    float4 v2 = p[l + 128];
    float ss = v0.x*v0.x + v0.y*v0.y + v0.z*v0.z + v0.w*v0.w
             + v1.x*v1.x + v1.y*v1.y + v1.z*v1.z + v1.w*v1.w
             + v2.x*v2.x + v2.y*v2.y + v2.z*v2.z + v2.w*v2.w;
    #pragma unroll
    for (int m = 1; m < 64; m <<= 1) ss += __shfl_xor(ss, m);
    const float sc = 0.125f / fmaxf(sqrtf(ss), EPSF);
    v0.x*=sc; v0.y*=sc; v0.z*=sc; v0.w*=sc;
    v1.x*=sc; v1.y*=sc; v1.z*=sc; v1.w*=sc;
    v2.x*=sc; v2.y*=sc; v2.z*=sc; v2.w*=sc;
    p[l] = v0;
    p[l + 64] = v1;
    p[l + 128] = v2;
}

extern "C" void kernel_launch(void* const* d_in, const int* in_sizes, int n_in,
                              void* d_out, int out_size, void* d_ws, size_t ws_size,
                              hipStream_t stream)
{
    const float* grids     = (const float*)d_in[0];
    const float* conv_w    = (const float*)d_in[1];
    const float* conv_b    = (const float*)d_in[2];
    const float* centroids = (const float*)d_in[3];
    float* out = (float*)d_out;

    // ws layout (bytes):
    //   ws_a    [0,         5,242,880)   64*64*640 bf16
    //   ws_asum [5,242,880, 5,406,720)   640*64 f32
    //   ws_w    [5,406,720, 5,505,024)   64*768 bf16
    unsigned short* ws_a    = (unsigned short*)d_ws;
    float*          ws_asum = (float*)((char*)d_ws + 5242880);
    unsigned short* ws_w    = (unsigned short*)((char*)d_ws + 5406720);

    hipLaunchKernelGGL(k_prep, dim3(24), dim3(256), 0, stream,
                       conv_w, ws_w, ws_a);
    hipLaunchKernelGGL(k_logits, dim3(NB * 10), dim3(256), 0, stream,
                       grids, ws_w, conv_b, ws_a, ws_asum);
    hipLaunchKernelGGL(k_vlad, dim3(NB * 12), dim3(256), 0, stream,
                       grids, ws_a, ws_asum, centroids, out);
    hipLaunchKernelGGL(kc_norm_kernel, dim3(NB * KR / 4), dim3(256), 0, stream, out);
}